// Round 6
// baseline (104.714 us; speedup 1.0000x reference)
//
#include <hip/hip_runtime.h>
#include <hip/hip_fp16.h>

typedef _Float16 f16;
typedef f16 f16x4 __attribute__((ext_vector_type(4)));
typedef f16 f16x8 __attribute__((ext_vector_type(8)));
typedef float f32x4 __attribute__((ext_vector_type(4)));

#define NN 1024

// workspace layout (bytes) — identical to round 5 (verified)
// img2: f16 [20][8192] — B-operand images in FRAGMENT-LINEAR order:
//   per (chunk c, wn half): 4096 f16 = [nt:4][ks:2][lane:64][8 f16],
//   element = B[n = wn*64+nt*16+lm][k = ks*32+q*8+s], lane = q*16+lm.
//   chunks 0..15 : W0^T j-chunks; 16,17 : W1 k-halves; 18,19 : W2 k-halves
#define IMG2_OFF  0
#define W8_OFF    327680                 // f32 [128] : W0[8][:] (norm row)
#define BIAS0_OFF 328192                 // f32 [32][128] : b0 + u[b] @ W0[0:8]

__global__ __launch_bounds__(256) void prep_kernel(
    const float* __restrict__ u,  const float* __restrict__ W0,
    const float* __restrict__ b0, const float* __restrict__ W1,
    const float* __restrict__ W2,
    f16* __restrict__ img2, float* __restrict__ w8v, float* __restrict__ bias0,
    float* __restrict__ outp)
{
    const int t = threadIdx.x;
    const int blk = blockIdx.x;
    if (blk < 160) {
        int flat = blk * 1024 + t * 4;
        int c   = flat >> 13;
        int rem = flat & 8191;
        int s0  = rem & 7;              // 0 or 4
        int lm  = (rem >> 3) & 15;
        int q   = (rem >> 7) & 3;
        int ks  = (rem >> 9) & 1;
        int nt  = (rem >> 10) & 3;
        int wn  = (rem >> 12) & 1;
        int n = wn * 64 + nt * 16 + lm;
        f16x4 v;
#pragma unroll
        for (int e = 0; e < 4; ++e) {
            int k = ks * 32 + q * 8 + s0 + e;
            float val;
            if (c < 16)       val = W0[(9 + c * 64 + k) * 128 + n];
            else if (c < 18)  val = W1[((c - 16) * 64 + k) * 128 + n];
            else              val = W2[((c - 18) * 64 + k) * 128 + n];
            v[e] = (f16)val;
        }
        *(f16x4*)&img2[flat] = v;
    } else if (blk < 176) {
        int idx = (blk - 160) * 256 + t;
        int b = idx >> 7, h = idx & 127;
        float s = b0[h];
#pragma unroll
        for (int g = 0; g < 8; ++g) s += u[b * 8 + g] * W0[g * 128 + h];
        bias0[idx] = s;
    } else if (blk == 176) {
        if (t < 128) w8v[t] = W0[8 * 128 + t];
    } else {
        int idx = (blk - 177) * 1024 + t * 4;
        if (idx < 12288) { float4 z = {0.f, 0.f, 0.f, 0.f}; *(float4*)&outp[idx] = z; }
    }
}

// i-tile 32 per block -> 1024 blocks -> 4 truly-resident blocks/CU.
// Wave tile: 16 i x 64 h. acc = 4 frags (16 VGPR). No full unroll (no spill).
__global__ __launch_bounds__(256, 4) void fused_kernel(
    const float* __restrict__ x, const float* __restrict__ b1p,
    const float* __restrict__ b2p, const f16* __restrict__ img2,
    const float* __restrict__ w8v, const float* __restrict__ bias0,
    float* __restrict__ outp)
{
    // ~18 KB LDS
    __shared__ __align__(16) f16 Dsh[2][32 * 64];   // 8 KB (XOR-swizzled)
    __shared__ __align__(16) f16 xjsh[1024 * 4];    // 8 KB: all x rows f16, [3]=0
    __shared__ __align__(16) float xi[32 * 4];      // this block's i-rows, f32
    __shared__ float normv[32];
    __shared__ float biass[128];
    __shared__ float w8s[128];

    const int t = threadIdx.x;
    const int b = blockIdx.x >> 5;
    const int i0 = (blockIdx.x & 31) * 32;

    // stage all 1024 x-rows as f16x4 (w=0): 3 float4 loads / thread
    {
        const float* xb = x + (size_t)b * NN * 3;
        float4 v0 = *(const float4*)(xb + t * 12);
        float4 v1 = *(const float4*)(xb + t * 12 + 4);
        float4 v2 = *(const float4*)(xb + t * 12 + 8);
        f16x4 r0; r0[0] = (f16)v0.x; r0[1] = (f16)v0.y; r0[2] = (f16)v0.z; r0[3] = (f16)0;
        f16x4 r1; r1[0] = (f16)v0.w; r1[1] = (f16)v1.x; r1[2] = (f16)v1.y; r1[3] = (f16)0;
        f16x4 r2; r2[0] = (f16)v1.z; r2[1] = (f16)v1.w; r2[2] = (f16)v2.x; r2[3] = (f16)0;
        f16x4 r3; r3[0] = (f16)v2.y; r3[1] = (f16)v2.z; r3[2] = (f16)v2.w; r3[3] = (f16)0;
        *(f16x4*)&xjsh[(t * 4 + 0) * 4] = r0;
        *(f16x4*)&xjsh[(t * 4 + 1) * 4] = r1;
        *(f16x4*)&xjsh[(t * 4 + 2) * 4] = r2;
        *(f16x4*)&xjsh[(t * 4 + 3) * 4] = r3;
    }
    if (t < 96) {
        int i = t / 3, d = t - i * 3;
        xi[i * 4 + d] = x[(size_t)(b * NN + i0 + i) * 3 + d];
    }
    if (t >= 128 && t < 256) { biass[t - 128] = bias0[b * 128 + (t - 128)]; }
    if (t >= 96 && t < 224 && t - 96 < 128) { w8s[t - 96] = w8v[t - 96]; }
    __syncthreads();
    if (t < 32) {
        float a0 = xi[t * 4], a1 = xi[t * 4 + 1], a2 = xi[t * 4 + 2];
        normv[t] = __builtin_amdgcn_sqrtf(a0 * a0 + a1 * a1 + a2 * a2);
    }

    const int lane = t & 63, wv = t >> 6;
    const int wm = wv >> 1, wn = wv & 1;     // wave tile: 16 i x 64 h
    const int lm = lane & 15, q = lane >> 4;

    // xi B-fragments for dot-MFMA (16x16x16, layout verified rounds 1-5):
    // lane(q==0,lm) holds coords of i = it*16+lm in k-slots 0..2.
    f16x4 bi[2];
#pragma unroll
    for (int it = 0; it < 2; ++it) {
        f16x4 v; v[0] = (f16)0; v[1] = (f16)0; v[2] = (f16)0; v[3] = (f16)0;
        if (q == 0) {
            int ii = it * 16 + lm;
            v[0] = (f16)xi[ii * 4];
            v[1] = (f16)xi[ii * 4 + 1];
            v[2] = (f16)xi[ii * 4 + 2];
        }
        bi[it] = v;
    }

    f32x4 acc[4];
    auto zero_acc = [&]() {
#pragma unroll
        for (int nt = 0; nt < 4; ++nt)
#pragma unroll
            for (int e = 0; e < 4; ++e) acc[nt][e] = 0.f;
    };
    zero_acc();

    // dot-MFMA for chunk jc -> sqrt -> packed b64 stores into Dsh[buf]
    // lane holds D[j = wv*16 + q*4 + r][i = it*16 + lm]
    auto dotstore = [&](int jc, int buf) {
        f16x4 ajv; ajv[0] = (f16)0; ajv[1] = (f16)0; ajv[2] = (f16)0; ajv[3] = (f16)0;
        if (q == 0)
            ajv = *(const f16x4*)&xjsh[(jc * 64 + wv * 16 + lm) * 4];
#pragma unroll
        for (int it = 0; it < 2; ++it) {
            f32x4 z; z[0] = 0.f; z[1] = 0.f; z[2] = 0.f; z[3] = 0.f;
            f32x4 cg = __builtin_amdgcn_mfma_f32_16x16x16f16(ajv, bi[it], z, 0, 0, 0);
            f16x4 dv;
#pragma unroll
            for (int r = 0; r < 4; ++r)
                dv[r] = (f16)__builtin_amdgcn_sqrtf(fmaxf(cg[r], 0.f));
            int row = it * 16 + lm;            // i (0..31)
            int colstart = wv * 16 + q * 4;    // j (0..63)
            int addr = row * 64 + (((colstart & ~7) ^ ((row & 7) << 3)) | (colstart & 7));
            *(f16x4*)&Dsh[buf][addr] = dv;
        }
    };

    // one K=64 GEMM step: A rows (i) from Dsh[dbuf], B (W) direct from img2 chunk c
    auto kstep = [&](int dbuf, int c, int dotjc, int dotbuf) {
        const f16* wb = img2 + (size_t)(c * 2 + wn) * 4096 + lane * 8;
        f16x8 bf[4][2];
#pragma unroll
        for (int nt = 0; nt < 4; ++nt)
#pragma unroll
            for (int ks = 0; ks < 2; ++ks)
                bf[nt][ks] = *(const f16x8*)(wb + (nt * 2 + ks) * 512);
        f16x8 af[2];
#pragma unroll
        for (int ks = 0; ks < 2; ++ks) {
            int row = wm * 16 + lm;
            int col = ks * 32 + q * 8;
            af[ks] = *(const f16x8*)(Dsh[dbuf] + row * 64 + (col ^ ((row & 7) << 3)));
        }
        if (dotjc >= 0) dotstore(dotjc, dotbuf);
#pragma unroll
        for (int ks = 0; ks < 2; ++ks)
#pragma unroll
            for (int nt = 0; nt < 4; ++nt)
                acc[nt] = __builtin_amdgcn_mfma_f32_16x16x32_f16(
                    af[ks], bf[nt][ks], acc[nt], 0, 0, 0);
    };

    // ---- prologue: D chunk 0 ----
    dotstore(0, 0);
    __syncthreads();

    // ---- layer-0 K-loop: one barrier per chunk ----
#pragma unroll 2
    for (int jc = 0; jc < 16; ++jc) {
        kstep(jc & 1, jc, (jc < 15) ? jc + 1 : -1, (jc & 1) ^ 1);
        __syncthreads();
    }

    // ---- epilogue 0: h0 = leaky(acc + bias + norm*w8) -> Dsh[wn] ----
    // lane holds C[i = wm*16 + q*4 + r][h = wn*64 + nt*16 + lm]
#pragma unroll
    for (int nt = 0; nt < 4; ++nt) {
        const int h = wn * 64 + nt * 16 + lm;
        const float bh = biass[h], w8h = w8s[h];
        const int hh = h & 63;
#pragma unroll
        for (int r = 0; r < 4; ++r) {
            int i = wm * 16 + q * 4 + r;
            float val = acc[nt][r] + bh + normv[i] * w8h;
            val = val > 0.f ? val : 0.01f * val;
            int addr = i * 64 + (((hh & ~7) ^ ((i & 7) << 3)) | (hh & 7));
            Dsh[wn][addr] = (f16)val;
        }
    }
    __syncthreads();

    // ---- layer 1: A = h0 (Dsh[0] = h 0..63, Dsh[1] = h 64..127), B = chunks 16,17
    zero_acc();
#pragma unroll
    for (int hb = 0; hb < 2; ++hb)
        kstep(hb, 16 + hb, -1, 0);
    __syncthreads();

    // ---- epilogue 1: h1 = leaky(acc + b1) -> Dsh[wn] ----
#pragma unroll
    for (int nt = 0; nt < 4; ++nt) {
        const int h = wn * 64 + nt * 16 + lm;
        const float bh = b1p[h];
        const int hh = h & 63;
#pragma unroll
        for (int r = 0; r < 4; ++r) {
            int i = wm * 16 + q * 4 + r;
            float val = acc[nt][r] + bh;
            val = val > 0.f ? val : 0.01f * val;
            int addr = i * 64 + (((hh & ~7) ^ ((i & 7) << 3)) | (hh & 7));
            Dsh[wn][addr] = (f16)val;
        }
    }
    __syncthreads();

    // ---- layer 2: B = chunks 18,19 ----
    zero_acc();
#pragma unroll
    for (int hb = 0; hb < 2; ++hb)
        kstep(hb, 18 + hb, -1, 0);

    // ---- contraction: out[b,o,d] += sum_i (fk+b2)*x_i / N ----
    float p[4][3];
#pragma unroll
    for (int nt = 0; nt < 4; ++nt)
#pragma unroll
        for (int d = 0; d < 3; ++d) p[nt][d] = 0.f;
    float bo[4];
#pragma unroll
    for (int nt = 0; nt < 4; ++nt) bo[nt] = b2p[wn * 64 + nt * 16 + lm];
#pragma unroll
    for (int r = 0; r < 4; ++r) {
        int i = wm * 16 + q * 4 + r;
        float x0 = xi[i * 4], x1 = xi[i * 4 + 1], x2 = xi[i * 4 + 2];
#pragma unroll
        for (int nt = 0; nt < 4; ++nt) {
            float fkv = acc[nt][r] + bo[nt];
            p[nt][0] = fmaf(fkv, x0, p[nt][0]);
            p[nt][1] = fmaf(fkv, x1, p[nt][1]);
            p[nt][2] = fmaf(fkv, x2, p[nt][2]);
        }
    }
#pragma unroll
    for (int nt = 0; nt < 4; ++nt)
#pragma unroll
        for (int d = 0; d < 3; ++d) {
            float s = p[nt][d];
            s += __shfl_xor(s, 16);
            s += __shfl_xor(s, 32);
            if (q == 0) {
                int o = wn * 64 + nt * 16 + lm;
                atomicAdd(&outp[(b * 128 + o) * 3 + d], s * (1.0f / 1024.0f));
            }
        }
}

extern "C" void kernel_launch(void* const* d_in, const int* in_sizes, int n_in,
                              void* d_out, int out_size, void* d_ws, size_t ws_size,
                              hipStream_t stream) {
    const float* x  = (const float*)d_in[0];
    const float* u  = (const float*)d_in[1];
    const float* W0 = (const float*)d_in[2];
    const float* b0 = (const float*)d_in[3];
    const float* W1 = (const float*)d_in[4];
    const float* b1 = (const float*)d_in[5];
    const float* W2 = (const float*)d_in[6];
    const float* b2 = (const float*)d_in[7];

    char* ws = (char*)d_ws;
    f16*   img2  = (f16*)(ws + IMG2_OFF);
    float* w8v   = (float*)(ws + W8_OFF);
    float* bias0 = (float*)(ws + BIAS0_OFF);
    float* out   = (float*)d_out;

    prep_kernel<<<189, 256, 0, stream>>>(u, W0, b0, W1, W2, img2, w8v, bias0, out);
    fused_kernel<<<1024, 256, 0, stream>>>(x, b1, b2, img2, w8v, bias0, out);
}